// Round 3
// baseline (482.454 us; speedup 1.0000x reference)
//
#include <hip/hip_runtime.h>

#define B_    64
#define C_    256
#define H_    56
#define W_    56
#define N_    6890
#define HW_   3136
#define NTILE 108          // ceil(6890/64) MLP point tiles
#define GRP_  8            // gather point-groups per batch
#define GPTS2 862          // ceil(6890/8)
#define PPT2  4            // ceil(862/256) points per thread

#define WB1_OFF (128*256)
#define WB2_OFF (128*256 + 64*384)
#define WTOT    (128*256 + 64*384 + 5*320)   // 58944 bf16 weight elements

typedef __attribute__((ext_vector_type(8))) __bf16 bf16x8;
typedef __attribute__((ext_vector_type(8))) unsigned short ushort8;
typedef __attribute__((ext_vector_type(4))) float f32x4;
typedef __attribute__((ext_vector_type(2))) float f32x2;
typedef __attribute__((ext_vector_type(4))) unsigned int uint4v;
typedef __attribute__((ext_vector_type(2))) unsigned int uint2v;

__device__ __forceinline__ unsigned short f2bf(float f) {
    unsigned int u = __builtin_bit_cast(unsigned int, f);
    u += 0x7FFFu + ((u >> 16) & 1u);   // RTNE
    return (unsigned short)(u >> 16);
}
__device__ __forceinline__ unsigned int pack2(float lo, float hi) {
    return (unsigned int)f2bf(lo) | ((unsigned int)f2bf(hi) << 16);
}
__device__ __forceinline__ float leaky(float v) { return v > 0.f ? v : 0.01f * v; }
__device__ __forceinline__ int pswz(int p) { return p ^ ((p >> 3) & 7); }  // pixel swizzle

// ============================ kernel 0: weight bf16 pack ============================
__global__ void wconv_kernel(const float* __restrict__ w0, const float* __restrict__ w1,
                             const float* __restrict__ w2, unsigned short* __restrict__ wb) {
    int i = blockIdx.x * 256 + threadIdx.x;
    if (i >= WTOT) return;
    float v = (i < WB1_OFF) ? w0[i] : (i < WB2_OFF) ? w1[i - WB1_OFF] : w2[i - WB2_OFF];
    wb[i] = f2bf(v);
}

// ============================ kernel 1: bilinear gather =============================
// grid = 512 blocks (batch pinned to XCD bid&7; 8 point-groups per batch).
// LDS: one 4-plane chunk, channel-interleaved [pixel(swizzled)][4ch] floats (50176 B)
// -> each bilinear corner = one ds_read_b128. Reg-prefetch of next chunk hides HBM.
template <bool XP>
__global__ __launch_bounds__(256, 2) void gather_kernel(
    const float* __restrict__ points, const float* __restrict__ im,
    float* __restrict__ out1, unsigned int* __restrict__ x2) {
    __shared__ float Ls[HW_ * 4];

    const int t   = threadIdx.x;
    const int bid = blockIdx.x;
    const int xcd = bid & 7;
    const int idx = bid >> 3;                 // 0..63
    const int b   = ((idx & 7) << 3) + xcd;   // batch: all its groups share one XCD
    const int grp = idx >> 3;                 // 0..7
    const int nbase = grp * GPTS2;

    // ---- per-point bilinear params (swizzled corner pixel indices) ----
    int   p00[PPT2], p01[PPT2], p10[PPT2], p11[PPT2];
    float w00[PPT2], w01[PPT2], w10[PPT2], w11[PPT2];
#pragma unroll
    for (int p = 0; p < PPT2; p++) {
        int ln = t + (p << 8);
        int n  = nbase + ln;
        bool ok = (ln < GPTS2) && (n < N_);
        int nl = ok ? n : 0;
        f32x2 pt = *(const f32x2*)(points + ((size_t)b * N_ + nl) * 2);
        float fx = fminf(fmaxf((pt.x + 1.f) * 27.5f, 0.f), 55.f);
        float fy = fminf(fmaxf((pt.y + 1.f) * 27.5f, 0.f), 55.f);
        float x0f = floorf(fx), y0f = floorf(fy);
        int x0 = (int)x0f, y0 = (int)y0f;
        float wx1 = fx - x0f, wy1 = fy - y0f;
        float wx0 = 1.f - wx1, wy0 = 1.f - wy1;
        bool hix = x0 >= W_ - 1;
        int   xb  = hix ? W_ - 2 : x0;
        float wxl = hix ? 0.f : wx0;
        float wxr = hix ? wx0 : wx1;
        int y0c = min(y0, H_ - 1);
        int y1c = min(y0 + 1, H_ - 1);
        w00[p] = wy0 * wxl; w01[p] = wy0 * wxr;
        w10[p] = wy1 * wxl; w11[p] = wy1 * wxr;
        int ia0 = y0c * W_ + xb, ia1 = y1c * W_ + xb;
        p00[p] = pswz(ia0); p01[p] = pswz(ia0 + 1);
        p10[p] = pswz(ia1); p11[p] = pswz(ia1 + 1);
    }

    const f32x4* imb4 = (const f32x4*)(im + (size_t)b * C_ * HW_);  // plane = 784 f32x4
    f32x4 rs[4][4];   // [pixel-group k][plane j]

#define GLOAD(CH) {                                                         \
    _Pragma("unroll")                                                       \
    for (int k = 0; k < 4; k++) {                                           \
        int g = t + (k << 8);                                               \
        if (g < 784) {                                                      \
            _Pragma("unroll")                                               \
            for (int j = 0; j < 4; j++)                                     \
                rs[k][j] = imb4[(size_t)((CH) * 4 + j) * 784 + g];          \
        }                                                                   \
    } }

    GLOAD(0);

    for (int ch = 0; ch < 64; ch++) {
        __syncthreads();                  // prior chunk's LDS reads complete
        // regs -> LDS, 4x4 transpose to [pixel][4ch], swizzled pixel index
#pragma unroll
        for (int k = 0; k < 4; k++) {
            int g = t + (k << 8);
            if (g < 784) {
#pragma unroll
                for (int i = 0; i < 4; i++) {
                    int pi = (g << 2) + i;
                    f32x4 v = {rs[0][0][0], 0.f, 0.f, 0.f};
                    v[0] = rs[k][0][i]; v[1] = rs[k][1][i];
                    v[2] = rs[k][2][i]; v[3] = rs[k][3][i];
                    *(f32x4*)(Ls + (pswz(pi) << 2)) = v;
                }
            }
        }
        __syncthreads();
        if (ch < 63) GLOAD(ch + 1);       // prefetch next chunk (hides under gather)

        const int c0 = ch * 4;
#pragma unroll
        for (int p = 0; p < PPT2; p++) {
            f32x4 q00 = *(const f32x4*)(Ls + (p00[p] << 2));
            f32x4 q01 = *(const f32x4*)(Ls + (p01[p] << 2));
            f32x4 q10 = *(const f32x4*)(Ls + (p10[p] << 2));
            f32x4 q11 = *(const f32x4*)(Ls + (p11[p] << 2));
            float v0 = w00[p]*q00[0] + w01[p]*q01[0] + w10[p]*q10[0] + w11[p]*q11[0];
            float v1 = w00[p]*q00[1] + w01[p]*q01[1] + w10[p]*q10[1] + w11[p]*q11[1];
            float v2 = w00[p]*q00[2] + w01[p]*q01[2] + w10[p]*q10[2] + w11[p]*q11[2];
            float v3 = w00[p]*q00[3] + w01[p]*q01[3] + w10[p]*q10[3] + w11[p]*q11[3];
            int ln = t + (p << 8);
            int n  = nbase + ln;
            if ((ln < GPTS2) && (n < N_)) {
                size_t ob = ((size_t)b * C_ + c0) * N_ + n;
                out1[ob]             = v0;
                out1[ob + N_]        = v1;
                out1[ob + 2 * N_]    = v2;
                out1[ob + 3 * N_]    = v3;
                if (XP) {
                    uint2v pk; pk[0] = pack2(v0, v1); pk[1] = pack2(v2, v3);
                    *(uint2v*)(x2 + ((size_t)((b << 6) + ch) * N_ + n) * 2) = pk;
                }
            }
        }
    }
#undef GLOAD
}

// ============================ kernel 2: MFMA MLP ====================================
__device__ __forceinline__ bf16x8 afrag_f32(const float* __restrict__ wp, int ldk,
                                            int rowbase, int k0, int lane, int nrows) {
    int i = rowbase + (lane & 15);
    int k = k0 + ((lane >> 4) << 3);
    ushort8 u;
    if (i < nrows) {
        const float* s = wp + (size_t)i * ldk + k;
#pragma unroll
        for (int j = 0; j < 8; j++) u[j] = f2bf(s[j]);
    } else {
#pragma unroll
        for (int j = 0; j < 8; j++) u[j] = 0;
    }
    return __builtin_bit_cast(bf16x8, u);
}
__device__ __forceinline__ bf16x8 afrag_bf(const unsigned short* __restrict__ wb, int ldk,
                                           int rowbase, int k0, int lane, int nrows) {
    int i = rowbase + (lane & 15);
    int k = k0 + ((lane >> 4) << 3);
    if (i < nrows) return __builtin_bit_cast(bf16x8, *(const ushort8*)(wb + (size_t)i * ldk + k));
    ushort8 z = {0, 0, 0, 0, 0, 0, 0, 0};
    return __builtin_bit_cast(bf16x8, z);
}

// B-fragment from swizzled LDS: buf[n][cd ^ ((n&7)<<2)], 4 dwords at k0
__device__ __forceinline__ bf16x8 bfrag(const unsigned int* buf, int rowstride_dw,
                                        int n, int k0) {
    int cd = (k0 >> 1) ^ ((n & 7) << 2);
    uint4v v = *(const uint4v*)(buf + n * rowstride_dw + cd);
    return __builtin_bit_cast(bf16x8, v);
}

template <bool XP, bool BF16W>
__global__ __launch_bounds__(256) void mlp_kernel(
    const float* __restrict__ pf, const unsigned int* __restrict__ x2,
    const float* __restrict__ w0, const float* __restrict__ b0,
    const float* __restrict__ w1, const float* __restrict__ b1,
    const float* __restrict__ w2, const float* __restrict__ b2,
    const unsigned short* __restrict__ wb,
    float* __restrict__ out0) {
    __shared__ unsigned int Xs[64 * 128];   // X  [n=64][c=256] bf16, swizzled (32KB)
    __shared__ unsigned int Y0s[64 * 64];   // Y0 [n][m=128] bf16 (16KB); Y1 aliased in

    const int t    = threadIdx.x;
    const int lane = t & 63;
    const int wave = t >> 6;
    const int bid  = blockIdx.x;
    const int b    = bid / NTILE;
    const int tile = bid - b * NTILE;
    const int n0   = tile * 64;

    const int nn_g = min(n0 + lane, N_ - 1);
    const int swz  = (lane & 7) << 2;

    if (XP) {
        // stage bf16 X tile: 16 x b64 coalesced loads + 8 conflict-free b128 LDS writes
#pragma unroll
        for (int j = 0; j < 8; j++) {
            int d2a = wave * 16 + 2 * j;
            const unsigned int* src = x2 + ((size_t)((b << 6) + d2a) * N_ + nn_g) * 2;
            uint2v q0 = *(const uint2v*)src;
            uint2v q1 = *(const uint2v*)(src + 2 * (size_t)N_);
            uint4v pk; pk[0] = q0[0]; pk[1] = q0[1]; pk[2] = q1[0]; pk[3] = q1[1];
            *(uint4v*)(Xs + lane * 128 + ((wave * 32 + 4 * j) ^ swz)) = pk;
        }
    } else {
        const float* pfb = pf + (size_t)b * C_ * N_;
#pragma unroll
        for (int g8 = 0; g8 < 8; g8++) {
            int c0 = wave * 64 + g8 * 8;
            float v[8];
#pragma unroll
            for (int j = 0; j < 8; j++) v[j] = pfb[(size_t)(c0 + j) * N_ + nn_g];
            uint4v pk;
            pk[0] = pack2(v[0], v[1]); pk[1] = pack2(v[2], v[3]);
            pk[2] = pack2(v[4], v[5]); pk[3] = pack2(v[6], v[7]);
            *(uint4v*)(Xs + lane * 128 + ((c0 >> 1) ^ swz)) = pk;
        }
    }

    // ---- layer 1 A preload ----
    bf16x8 a1[2][8];
#pragma unroll
    for (int mt = 0; mt < 2; mt++)
#pragma unroll
        for (int ks = 0; ks < 8; ks++)
            a1[mt][ks] = BF16W ? afrag_bf(wb, 256, (wave * 2 + mt) * 16, ks * 32, lane, 1 << 30)
                               : afrag_f32(w0, 256, (wave * 2 + mt) * 16, ks * 32, lane, 1 << 30);

    __syncthreads();

    const int cl = lane & 15;
    const int rh = lane >> 4;
    const int kq = rh << 3;

    // ---- layer 1: Y0[128,64] = leaky(W0 @ X + b0) ----
    f32x4 acc1[2][4] = {};
#pragma unroll
    for (int ks = 0; ks < 8; ks++) {
        bf16x8 bx[4];
#pragma unroll
        for (int nt = 0; nt < 4; nt++)
            bx[nt] = bfrag(Xs, 128, nt * 16 + cl, ks * 32 + kq);
#pragma unroll
        for (int mt = 0; mt < 2; mt++)
#pragma unroll
            for (int nt = 0; nt < 4; nt++)
                acc1[mt][nt] = __builtin_amdgcn_mfma_f32_16x16x32_bf16(
                    a1[mt][ks], bx[nt], acc1[mt][nt], 0, 0, 0);
    }

#pragma unroll
    for (int mt = 0; mt < 2; mt++) {
        int m0 = (wave * 2 + mt) * 16 + (rh << 2);
        f32x4 bias = *(const f32x4*)(b0 + m0);
#pragma unroll
        for (int nt = 0; nt < 4; nt++) {
            int nn = nt * 16 + cl;
            float v0 = leaky(acc1[mt][nt][0] + bias[0]);
            float v1 = leaky(acc1[mt][nt][1] + bias[1]);
            float v2 = leaky(acc1[mt][nt][2] + bias[2]);
            float v3 = leaky(acc1[mt][nt][3] + bias[3]);
            int md = (m0 >> 1) ^ ((nn & 7) << 2);
            uint2v pk; pk[0] = pack2(v0, v1); pk[1] = pack2(v2, v3);
            *(uint2v*)(Y0s + nn * 64 + md) = pk;
        }
    }

    // ---- layer 2 A preload: K = 384 = [Y0(128) | X(256)] ----
    bf16x8 a2[12];
#pragma unroll
    for (int ks = 0; ks < 12; ks++)
        a2[ks] = BF16W ? afrag_bf(wb + WB1_OFF, 384, wave * 16, ks * 32, lane, 1 << 30)
                       : afrag_f32(w1, 384, wave * 16, ks * 32, lane, 1 << 30);

    __syncthreads();

    f32x4 acc2[4] = {};
#pragma unroll
    for (int ks = 0; ks < 12; ks++) {
#pragma unroll
        for (int nt = 0; nt < 4; nt++) {
            bf16x8 bx = (ks < 4) ? bfrag(Y0s, 64, nt * 16 + cl, ks * 32 + kq)
                                 : bfrag(Xs, 128, nt * 16 + cl, (ks - 4) * 32 + kq);
            acc2[nt] = __builtin_amdgcn_mfma_f32_16x16x32_bf16(a2[ks], bx, acc2[nt], 0, 0, 0);
        }
    }

    // layer 3 A preload (W2 zero-padded to 16 rows); K = 320 = [Y1(64) | X(256)]
    bf16x8 a3[10];
#pragma unroll
    for (int ks = 0; ks < 10; ks++)
        a3[ks] = BF16W ? afrag_bf(wb + WB2_OFF, 320, 0, ks * 32, lane, 5)
                       : afrag_f32(w2, 320, 0, ks * 32, lane, 5);

    __syncthreads();   // all waves done READING Y0s before Y1 overwrites it

    // ---- epilogue 2 -> Y1s (aliases Y0s) ----
    {
        int m0 = wave * 16 + (rh << 2);
        f32x4 bias = *(const f32x4*)(b1 + m0);
#pragma unroll
        for (int nt = 0; nt < 4; nt++) {
            int nn = nt * 16 + cl;
            float v0 = leaky(acc2[nt][0] + bias[0]);
            float v1 = leaky(acc2[nt][1] + bias[1]);
            float v2 = leaky(acc2[nt][2] + bias[2]);
            float v3 = leaky(acc2[nt][3] + bias[3]);
            int md = (m0 >> 1) ^ ((nn & 7) << 2);
            uint2v pk; pk[0] = pack2(v0, v1); pk[1] = pack2(v2, v3);
            *(uint2v*)(Y0s + nn * 32 + md) = pk;   // Y1 layout: [n][32 dwords]
        }
    }

    __syncthreads();

    // ---- layer 3: each wave owns one 16-col N-tile ----
    {
        int nn = wave * 16 + cl;
        f32x4 acc3 = {};
#pragma unroll
        for (int ks = 0; ks < 10; ks++) {
            bf16x8 bx = (ks < 2) ? bfrag(Y0s, 32, nn, ks * 32 + kq)
                                 : bfrag(Xs, 128, nn, (ks - 2) * 32 + kq);
            acc3 = __builtin_amdgcn_mfma_f32_16x16x32_bf16(a3[ks], bx, acc3, 0, 0, 0);
        }
        int gn2 = n0 + nn;
        if (gn2 < N_) {
#pragma unroll
            for (int r = 0; r < 4; r++) {
                int m = (rh << 2) + r;
                if (m < 5) {
                    float v = acc3[r] + b2[m];
                    v = v > 0.f ? v : 0.f;   // final relu
                    out0[((size_t)b * 5 + m) * N_ + gn2] = v;
                }
            }
        }
    }
}

extern "C" void kernel_launch(void* const* d_in, const int* in_sizes, int n_in,
                              void* d_out, int out_size, void* d_ws, size_t ws_size,
                              hipStream_t stream) {
    const float* points = (const float*)d_in[0];
    const float* im     = (const float*)d_in[1];
    const float* w0     = (const float*)d_in[2];
    const float* b0     = (const float*)d_in[3];
    const float* w1     = (const float*)d_in[4];
    const float* b1     = (const float*)d_in[5];
    const float* w2     = (const float*)d_in[6];
    const float* b2     = (const float*)d_in[7];
    float* out0 = (float*)d_out;                   // mesh_align_feat [64][5*6890]
    float* out1 = out0 + (size_t)B_ * 5 * N_;      // point_feat      [64][256][6890]

    const size_t XBYTES = (size_t)B_ * 64 * N_ * 2 * 4;   // bf16 X, 225.8 MB
    const size_t WBYTES = (size_t)WTOT * 2;
    const bool xok = (d_ws != nullptr) && (ws_size >= XBYTES + WBYTES);
    const bool wok = xok || ((d_ws != nullptr) && (ws_size >= WBYTES));
    unsigned int*   x2 = (unsigned int*)d_ws;
    unsigned short* wb = xok ? (unsigned short*)((char*)d_ws + XBYTES)
                             : (unsigned short*)d_ws;

    if (wok) {
        hipLaunchKernelGGL(wconv_kernel, dim3((WTOT + 255) / 256), dim3(256), 0, stream,
                           w0, w1, w2, wb);
    }
    if (xok) {
        hipLaunchKernelGGL(gather_kernel<true>, dim3(B_ * GRP_), dim3(256), 0, stream,
                           points, im, out1, x2);
        hipLaunchKernelGGL((mlp_kernel<true, true>), dim3(B_ * NTILE), dim3(256), 0, stream,
                           out1, x2, w0, b0, w1, b1, w2, b2, wb, out0);
    } else {
        hipLaunchKernelGGL(gather_kernel<false>, dim3(B_ * GRP_), dim3(256), 0, stream,
                           points, im, out1, (unsigned int*)nullptr);
        if (wok) {
            hipLaunchKernelGGL((mlp_kernel<false, true>), dim3(B_ * NTILE), dim3(256), 0, stream,
                               out1, (const unsigned int*)nullptr, w0, b0, w1, b1, w2, b2, wb, out0);
        } else {
            hipLaunchKernelGGL((mlp_kernel<false, false>), dim3(B_ * NTILE), dim3(256), 0, stream,
                               out1, (const unsigned int*)nullptr, w0, b0, w1, b1, w2, b2,
                               (const unsigned short*)nullptr, out0);
        }
    }
}

// Round 4
// 318.213 us; speedup vs baseline: 1.5161x; 1.5161x over previous
//
#include <hip/hip_runtime.h>

#define B_    64
#define C_    256
#define H_    56
#define W_    56
#define N_    6890
#define HW_   3136
#define NTILE 108          // ceil(6890/64) MLP point tiles

#define WB1_OFF (128*256)
#define WB2_OFF (128*256 + 64*384)
#define WTOT    (128*256 + 64*384 + 5*320)   // 58944 bf16 weight elements

typedef __attribute__((ext_vector_type(8))) __bf16 bf16x8;
typedef __attribute__((ext_vector_type(8))) unsigned short ushort8;
typedef __attribute__((ext_vector_type(4))) float f32x4;
typedef __attribute__((ext_vector_type(2))) float f32x2;
typedef __attribute__((ext_vector_type(4))) unsigned int uint4v;
typedef __attribute__((ext_vector_type(2))) unsigned int uint2v;

__device__ __forceinline__ unsigned short f2bf(float f) {
    unsigned int u = __builtin_bit_cast(unsigned int, f);
    u += 0x7FFFu + ((u >> 16) & 1u);   // RTNE
    return (unsigned short)(u >> 16);
}
__device__ __forceinline__ unsigned int pack2(float lo, float hi) {
    return (unsigned int)f2bf(lo) | ((unsigned int)f2bf(hi) << 16);
}
__device__ __forceinline__ float leaky(float v) { return v > 0.f ? v : 0.01f * v; }
__device__ __forceinline__ int pswz(int p) { return p ^ ((p >> 3) & 7); }  // pixel swizzle

// ============================ kernel 0: weight bf16 pack ============================
__global__ void wconv_kernel(const float* __restrict__ w0, const float* __restrict__ w1,
                             const float* __restrict__ w2, unsigned short* __restrict__ wb) {
    int i = blockIdx.x * 256 + threadIdx.x;
    if (i >= WTOT) return;
    float v = (i < WB1_OFF) ? w0[i] : (i < WB2_OFF) ? w1[i - WB1_OFF] : w2[i - WB2_OFF];
    wb[i] = f2bf(v);
}

// ============================ kernel 1: bilinear gather =============================
// One block per (batch, 4-channel chunk): 4096 blocks x 512 threads.
// Stage 4 planes (50 KB) to LDS ONCE -> image read from HBM exactly once, coalesced.
// LDS layout [pixel(swizzled)][4ch] -> each bilinear corner is one ds_read_b128.
// Then gather ALL 6890 points for these 4 channels; no loops over channels, 1 barrier.
__global__ __launch_bounds__(512, 6) void gather_kernel(
    const float* __restrict__ points, const float* __restrict__ im,
    float* __restrict__ out1) {
    __shared__ float Ls[HW_ * 4];   // 50176 B

    const int t   = threadIdx.x;
    const int bid = blockIdx.x;
    // batch pinned to one XCD (bid&7 constant across its 64 chunk-blocks) -> points L2-reuse
    const int b  = ((bid & 7) << 3) | ((bid >> 3) & 7);
    const int ch = bid >> 6;                  // 0..63 (4-channel chunk)

    // ---- stage 4 planes, transposing to [pixel][4ch] with pixel swizzle ----
    const f32x4* im4 = (const f32x4*)(im + ((size_t)b * C_ + ch * 4) * HW_);
#pragma unroll
    for (int g0 = 0; g0 < 2; g0++) {
        int g = t + (g0 << 9);
        if (g < 784) {                         // 784 f32x4 groups per plane
            f32x4 r0 = im4[g];
            f32x4 r1 = im4[784 + g];
            f32x4 r2 = im4[1568 + g];
            f32x4 r3 = im4[2352 + g];
#pragma unroll
            for (int i = 0; i < 4; i++) {
                f32x4 v; v[0] = r0[i]; v[1] = r1[i]; v[2] = r2[i]; v[3] = r3[i];
                *(f32x4*)(Ls + (pswz((g << 2) + i) << 2)) = v;
            }
        }
    }
    __syncthreads();

    // ---- gather all points for these 4 channels ----
    const float* ptb = points + (size_t)b * N_ * 2;
    const size_t ob0 = ((size_t)b * C_ + ch * 4) * N_;
#pragma unroll 2
    for (int p = 0; p < 14; p++) {            // 14*512 >= 6890
        int n = t + (p << 9);
        if (n < N_) {
            f32x2 pt = *(const f32x2*)(ptb + 2 * n);
            float fx = fminf(fmaxf((pt.x + 1.f) * 27.5f, 0.f), 55.f);
            float fy = fminf(fmaxf((pt.y + 1.f) * 27.5f, 0.f), 55.f);
            float x0f = floorf(fx), y0f = floorf(fy);
            int x0 = (int)x0f, y0 = (int)y0f;
            float wx1 = fx - x0f, wy1 = fy - y0f;
            float wx0 = 1.f - wx1, wy0 = 1.f - wy1;
            bool hix = x0 >= W_ - 1;          // fx==55 edge: weight moves to right tap
            int   xb  = hix ? W_ - 2 : x0;
            float wxl = hix ? 0.f : wx0;
            float wxr = hix ? wx0 : wx1;
            int y0c = min(y0, H_ - 1);
            int y1c = min(y0 + 1, H_ - 1);    // fy==55 edge: wy1==0
            float w00 = wy0 * wxl, w01 = wy0 * wxr;
            float w10 = wy1 * wxl, w11 = wy1 * wxr;
            int ia0 = y0c * W_ + xb, ia1 = y1c * W_ + xb;

            f32x4 q00 = *(const f32x4*)(Ls + (pswz(ia0)     << 2));
            f32x4 q01 = *(const f32x4*)(Ls + (pswz(ia0 + 1) << 2));
            f32x4 q10 = *(const f32x4*)(Ls + (pswz(ia1)     << 2));
            f32x4 q11 = *(const f32x4*)(Ls + (pswz(ia1 + 1) << 2));
            float v0 = w00*q00[0] + w01*q01[0] + w10*q10[0] + w11*q11[0];
            float v1 = w00*q00[1] + w01*q01[1] + w10*q10[1] + w11*q11[1];
            float v2 = w00*q00[2] + w01*q01[2] + w10*q10[2] + w11*q11[2];
            float v3 = w00*q00[3] + w01*q01[3] + w10*q10[3] + w11*q11[3];
            out1[ob0 + n]          = v0;      // coalesced over lanes (consecutive n)
            out1[ob0 + N_ + n]     = v1;
            out1[ob0 + 2*N_ + n]   = v2;
            out1[ob0 + 3*N_ + n]   = v3;
        }
    }
}

// ============================ kernel 2: MFMA MLP ====================================
__device__ __forceinline__ bf16x8 afrag_f32(const float* __restrict__ wp, int ldk,
                                            int rowbase, int k0, int lane, int nrows) {
    int i = rowbase + (lane & 15);
    int k = k0 + ((lane >> 4) << 3);
    ushort8 u;
    if (i < nrows) {
        const float* s = wp + (size_t)i * ldk + k;
#pragma unroll
        for (int j = 0; j < 8; j++) u[j] = f2bf(s[j]);
    } else {
#pragma unroll
        for (int j = 0; j < 8; j++) u[j] = 0;
    }
    return __builtin_bit_cast(bf16x8, u);
}
__device__ __forceinline__ bf16x8 afrag_bf(const unsigned short* __restrict__ wb, int ldk,
                                           int rowbase, int k0, int lane, int nrows) {
    int i = rowbase + (lane & 15);
    int k = k0 + ((lane >> 4) << 3);
    if (i < nrows) return __builtin_bit_cast(bf16x8, *(const ushort8*)(wb + (size_t)i * ldk + k));
    ushort8 z = {0, 0, 0, 0, 0, 0, 0, 0};
    return __builtin_bit_cast(bf16x8, z);
}

// B-fragment from swizzled LDS: buf[n][cd ^ ((n&7)<<2)], 4 dwords at k0
__device__ __forceinline__ bf16x8 bfrag(const unsigned int* buf, int rowstride_dw,
                                        int n, int k0) {
    int cd = (k0 >> 1) ^ ((n & 7) << 2);
    uint4v v = *(const uint4v*)(buf + n * rowstride_dw + cd);
    return __builtin_bit_cast(bf16x8, v);
}

template <bool BF16W>
__global__ __launch_bounds__(256) void mlp_kernel(
    const float* __restrict__ pf,
    const float* __restrict__ w0, const float* __restrict__ b0,
    const float* __restrict__ w1, const float* __restrict__ b1,
    const float* __restrict__ w2, const float* __restrict__ b2,
    const unsigned short* __restrict__ wb,
    float* __restrict__ out0) {
    __shared__ unsigned int Xs[64 * 128];   // X  [n=64][c=256] bf16, swizzled (32KB)
    __shared__ unsigned int Y0s[64 * 64];   // Y0 [n][m=128] bf16 (16KB); Y1 aliased in

    const int t    = threadIdx.x;
    const int lane = t & 63;
    const int wave = t >> 6;
    const int bid  = blockIdx.x;
    const int b    = bid / NTILE;
    const int tile = bid - b * NTILE;
    const int n0   = tile * 64;

    const int nn_g = min(n0 + lane, N_ - 1);
    const int swz  = (lane & 7) << 2;

    // ---- stage X tile from point_feat (coalesced scalar-per-lane) ----
    const float* pfb = pf + (size_t)b * C_ * N_;
#pragma unroll
    for (int g8 = 0; g8 < 8; g8++) {
        int c0 = wave * 64 + g8 * 8;
        float v[8];
#pragma unroll
        for (int j = 0; j < 8; j++) v[j] = pfb[(size_t)(c0 + j) * N_ + nn_g];
        uint4v pk;
        pk[0] = pack2(v[0], v[1]); pk[1] = pack2(v[2], v[3]);
        pk[2] = pack2(v[4], v[5]); pk[3] = pack2(v[6], v[7]);
        *(uint4v*)(Xs + lane * 128 + ((c0 >> 1) ^ swz)) = pk;
    }

    // ---- layer 1 A preload ----
    bf16x8 a1[2][8];
#pragma unroll
    for (int mt = 0; mt < 2; mt++)
#pragma unroll
        for (int ks = 0; ks < 8; ks++)
            a1[mt][ks] = BF16W ? afrag_bf(wb, 256, (wave * 2 + mt) * 16, ks * 32, lane, 1 << 30)
                               : afrag_f32(w0, 256, (wave * 2 + mt) * 16, ks * 32, lane, 1 << 30);

    __syncthreads();

    const int cl = lane & 15;
    const int rh = lane >> 4;
    const int kq = rh << 3;

    // ---- layer 1: Y0[128,64] = leaky(W0 @ X + b0) ----
    f32x4 acc1[2][4] = {};
#pragma unroll
    for (int ks = 0; ks < 8; ks++) {
        bf16x8 bx[4];
#pragma unroll
        for (int nt = 0; nt < 4; nt++)
            bx[nt] = bfrag(Xs, 128, nt * 16 + cl, ks * 32 + kq);
#pragma unroll
        for (int mt = 0; mt < 2; mt++)
#pragma unroll
            for (int nt = 0; nt < 4; nt++)
                acc1[mt][nt] = __builtin_amdgcn_mfma_f32_16x16x32_bf16(
                    a1[mt][ks], bx[nt], acc1[mt][nt], 0, 0, 0);
    }

#pragma unroll
    for (int mt = 0; mt < 2; mt++) {
        int m0 = (wave * 2 + mt) * 16 + (rh << 2);
        f32x4 bias = *(const f32x4*)(b0 + m0);
#pragma unroll
        for (int nt = 0; nt < 4; nt++) {
            int nn = nt * 16 + cl;
            float v0 = leaky(acc1[mt][nt][0] + bias[0]);
            float v1 = leaky(acc1[mt][nt][1] + bias[1]);
            float v2 = leaky(acc1[mt][nt][2] + bias[2]);
            float v3 = leaky(acc1[mt][nt][3] + bias[3]);
            int md = (m0 >> 1) ^ ((nn & 7) << 2);
            uint2v pk; pk[0] = pack2(v0, v1); pk[1] = pack2(v2, v3);
            *(uint2v*)(Y0s + nn * 64 + md) = pk;
        }
    }

    // ---- layer 2 A preload: K = 384 = [Y0(128) | X(256)] ----
    bf16x8 a2[12];
#pragma unroll
    for (int ks = 0; ks < 12; ks++)
        a2[ks] = BF16W ? afrag_bf(wb + WB1_OFF, 384, wave * 16, ks * 32, lane, 1 << 30)
                       : afrag_f32(w1, 384, wave * 16, ks * 32, lane, 1 << 30);

    __syncthreads();

    f32x4 acc2[4] = {};
#pragma unroll
    for (int ks = 0; ks < 12; ks++) {
#pragma unroll
        for (int nt = 0; nt < 4; nt++) {
            bf16x8 bx = (ks < 4) ? bfrag(Y0s, 64, nt * 16 + cl, ks * 32 + kq)
                                 : bfrag(Xs, 128, nt * 16 + cl, (ks - 4) * 32 + kq);
            acc2[nt] = __builtin_amdgcn_mfma_f32_16x16x32_bf16(a2[ks], bx, acc2[nt], 0, 0, 0);
        }
    }

    // layer 3 A preload (W2 zero-padded to 16 rows); K = 320 = [Y1(64) | X(256)]
    bf16x8 a3[10];
#pragma unroll
    for (int ks = 0; ks < 10; ks++)
        a3[ks] = BF16W ? afrag_bf(wb + WB2_OFF, 320, 0, ks * 32, lane, 5)
                       : afrag_f32(w2, 320, 0, ks * 32, lane, 5);

    __syncthreads();   // all waves done READING Y0s before Y1 overwrites it

    // ---- epilogue 2 -> Y1s (aliases Y0s) ----
    {
        int m0 = wave * 16 + (rh << 2);
        f32x4 bias = *(const f32x4*)(b1 + m0);
#pragma unroll
        for (int nt = 0; nt < 4; nt++) {
            int nn = nt * 16 + cl;
            float v0 = leaky(acc2[nt][0] + bias[0]);
            float v1 = leaky(acc2[nt][1] + bias[1]);
            float v2 = leaky(acc2[nt][2] + bias[2]);
            float v3 = leaky(acc2[nt][3] + bias[3]);
            int md = (m0 >> 1) ^ ((nn & 7) << 2);
            uint2v pk; pk[0] = pack2(v0, v1); pk[1] = pack2(v2, v3);
            *(uint2v*)(Y0s + nn * 32 + md) = pk;   // Y1 layout: [n][32 dwords]
        }
    }

    __syncthreads();

    // ---- layer 3: each wave owns one 16-col N-tile ----
    {
        int nn = wave * 16 + cl;
        f32x4 acc3 = {};
#pragma unroll
        for (int ks = 0; ks < 10; ks++) {
            bf16x8 bx = (ks < 2) ? bfrag(Y0s, 32, nn, ks * 32 + kq)
                                 : bfrag(Xs, 128, nn, (ks - 2) * 32 + kq);
            acc3 = __builtin_amdgcn_mfma_f32_16x16x32_bf16(a3[ks], bx, acc3, 0, 0, 0);
        }
        int gn2 = n0 + nn;
        if (gn2 < N_) {
#pragma unroll
            for (int r = 0; r < 4; r++) {
                int m = (rh << 2) + r;
                if (m < 5) {
                    float v = acc3[r] + b2[m];
                    v = v > 0.f ? v : 0.f;   // final relu
                    out0[((size_t)b * 5 + m) * N_ + gn2] = v;
                }
            }
        }
    }
}

extern "C" void kernel_launch(void* const* d_in, const int* in_sizes, int n_in,
                              void* d_out, int out_size, void* d_ws, size_t ws_size,
                              hipStream_t stream) {
    const float* points = (const float*)d_in[0];
    const float* im     = (const float*)d_in[1];
    const float* w0     = (const float*)d_in[2];
    const float* b0     = (const float*)d_in[3];
    const float* w1     = (const float*)d_in[4];
    const float* b1     = (const float*)d_in[5];
    const float* w2     = (const float*)d_in[6];
    const float* b2     = (const float*)d_in[7];
    float* out0 = (float*)d_out;                   // mesh_align_feat [64][5*6890]
    float* out1 = out0 + (size_t)B_ * 5 * N_;      // point_feat      [64][256][6890]

    const size_t WBYTES = (size_t)WTOT * 2;
    const bool wok = (d_ws != nullptr) && (ws_size >= WBYTES);
    unsigned short* wb = (unsigned short*)d_ws;

    if (wok) {
        hipLaunchKernelGGL(wconv_kernel, dim3((WTOT + 255) / 256), dim3(256), 0, stream,
                           w0, w1, w2, wb);
    }
    hipLaunchKernelGGL(gather_kernel, dim3(B_ * 64), dim3(512), 0, stream,
                       points, im, out1);
    if (wok) {
        hipLaunchKernelGGL(mlp_kernel<true>, dim3(B_ * NTILE), dim3(256), 0, stream,
                           out1, w0, b0, w1, b1, w2, b2, wb, out0);
    } else {
        hipLaunchKernelGGL(mlp_kernel<false>, dim3(B_ * NTILE), dim3(256), 0, stream,
                           out1, w0, b0, w1, b1, w2, b2, (const unsigned short*)nullptr, out0);
    }
}